// Round 13
// baseline (198.686 us; speedup 1.0000x reference)
//
#include <hip/hip_runtime.h>

// EdgeModel: out = relu(x@W1+b1)@W2 + b2 + x, x = [src|dest|ea|u[batch]].
// E=1e6, dims 128. bf16 MFMA 16x16x32, fp32 accum.
// R13: R5/R12 structure with TILE_M 64 -> 32. Halves per-wave accumulator
// AGPRs (64->32) and staging regs (32->16) so the NATURAL allocation drops
// to ~125 unified regs -> 3-4 waves/SIMD without forced launch bounds
// (every forced bound spilled: R6/R7/R9/R10/R11). Same swizzles, same
// transposed GEMMs, same epilogue; 4 blocks/CU at 16 KB LDS each.

#define E_TOTAL   1000000
#define TILE_M    32
#define NUM_TILES (E_TOTAL / TILE_M)   // 31250
#define GRID      2048

typedef __attribute__((ext_vector_type(8))) __bf16 bf16x8;
typedef __attribute__((ext_vector_type(4))) __bf16 bf16x4;
typedef __attribute__((ext_vector_type(4))) float  f32x4;

__device__ inline bf16x8 pack8(f32x4 v0, f32x4 v1) {
    bf16x8 r;
    r[0] = (__bf16)v0[0]; r[1] = (__bf16)v0[1];
    r[2] = (__bf16)v0[2]; r[3] = (__bf16)v0[3];
    r[4] = (__bf16)v1[0]; r[5] = (__bf16)v1[1];
    r[6] = (__bf16)v1[2]; r[7] = (__bf16)v1[3];
    return r;
}

// row-major [32][128] bf16, 16 groups of 8/row, group XOR (row&15):
// all b128 reads conflict-free (same math as the 64-row version).
__device__ inline int swz(int row, int group) {
    return (row * 16 + (group ^ (row & 15))) * 8;
}

__global__ __launch_bounds__(256, 2)
void edge_mlp(const float* __restrict__ gsrc,
              const float* __restrict__ gdst,
              const float* __restrict__ gea,
              const float* __restrict__ gu,
              const int*   __restrict__ gbatch,
              const float* __restrict__ gw1,
              const float* __restrict__ gb1,
              const float* __restrict__ gw2,
              const float* __restrict__ gb2,
              float* __restrict__ gout)
{
    __shared__ __align__(16) __bf16 xs[TILE_M * 128];   // 8 KB x tile (swizzled)
    __shared__ __align__(16) __bf16 hl[TILE_M * 128];   // 8 KB h tile (swizzled)

    const int tid  = threadIdx.x;
    const int lane = tid & 63;
    const int wid  = tid >> 6;     // wave owns hidden/out-dim rows [wb,wb+32)
    const int l15  = lane & 15;
    const int g    = lane >> 4;
    const int wb   = wid * 32;

    // ---- W1^T and W2^T as A-fragments (persistent, 64 regs):
    //      lane holds W^T[row = wb+m*16+l15][k = ks*32+g*8+j] = gw[k*128+row]
    bf16x8 w1t[2][4], w2t[2][4];
#pragma unroll
    for (int m = 0; m < 2; ++m)
#pragma unroll
        for (int ks = 0; ks < 4; ++ks) {
            bf16x8 t1, t2;
#pragma unroll
            for (int j = 0; j < 8; ++j) {
                const int k = ks * 32 + g * 8 + j;
                const int r = wb + m * 16 + l15;
                t1[j] = (__bf16)gw1[k * 128 + r];
                t2[j] = (__bf16)gw2[k * 128 + r];
            }
            w1t[m][ks] = t1;
            w2t[m][ks] = t2;
        }

    // ---- b1 along C rows (persistent; b2 reloaded per tile, R12) ----
    f32x4 b1v[2];
#pragma unroll
    for (int m = 0; m < 2; ++m)
#pragma unroll
        for (int r = 0; r < 4; ++r)
            b1v[m][r] = gb1[wb + m * 16 + g * 4 + r];

    // ---- staging: thread t owns edge-row t>>3, source-group pair
    //      {ssub, ssub+8} (8 floats each). Groups 0-3 src, 4-7 dest,
    //      8-11 ea, 12-15 u[batch]. ----
    const int srow = tid >> 3;     // 0..31
    const int ssub = tid & 7;      // 0..7
    const int soff = (ssub & 3) * 8;

    f32x4 pre[2][2];               // chunk A = group ssub, chunk B = group ssub+8
    auto load_pre = [&](int t) {
        const int e = t * TILE_M + srow;
        const int bi = gbatch[e];
        const float* pA = ((ssub < 4) ? gsrc : gdst) + (size_t)e * 32 + soff;
        const float* pB = (ssub < 4) ? (gea + (size_t)e * 32 + soff)
                                     : (gu + (size_t)bi * 32 + soff);
        pre[0][0] = *(const f32x4*)pA; pre[0][1] = *(const f32x4*)(pA + 4);
        pre[1][0] = *(const f32x4*)pB; pre[1][1] = *(const f32x4*)(pB + 4);
    };

    int tile = blockIdx.x;
    load_pre(tile);

    while (true) {
        // ---- stage x tile into LDS (bf16, swizzled, 2 b128/thread) ----
        *(bf16x8*)&xs[swz(srow, ssub)]     = pack8(pre[0][0], pre[0][1]);
        *(bf16x8*)&xs[swz(srow, ssub + 8)] = pack8(pre[1][0], pre[1][1]);
        __syncthreads();                                   // bar1

        const int  nxt  = tile + GRID;
        const bool have = nxt < NUM_TILES;
        if (have) load_pre(nxt);

        // ---- GEMM1^T: h^T = W1^T @ x^T + b1 ----
        f32x4 acc[2][2];
#pragma unroll
        for (int m = 0; m < 2; ++m)
#pragma unroll
            for (int n = 0; n < 2; ++n)
                acc[m][n] = b1v[m];
#pragma unroll
        for (int ks = 0; ks < 4; ++ks) {
            bf16x8 bf[2];
#pragma unroll
            for (int n = 0; n < 2; ++n)
                bf[n] = *(const bf16x8*)&xs[swz(n * 16 + l15, ks * 4 + g)];
#pragma unroll
            for (int m = 0; m < 2; ++m)
#pragma unroll
                for (int n = 0; n < 2; ++n)
                    acc[m][n] = __builtin_amdgcn_mfma_f32_16x16x32_bf16(
                        w1t[m][ks], bf[n], acc[m][n], 0, 0, 0);
        }

        // ---- ReLU + pack + h -> LDS (b64: 4 consecutive hidden dims) ----
#pragma unroll
        for (int m = 0; m < 2; ++m)
#pragma unroll
            for (int n = 0; n < 2; ++n) {
                f32x4 v = acc[m][n];
                bf16x4 h4;
#pragma unroll
                for (int r = 0; r < 4; ++r) {
                    float x = v[r];
                    h4[r] = (__bf16)(x > 0.f ? x : 0.f);
                }
                const int hid = wb + m * 16 + 4 * g;       // 4-aligned
                *(bf16x4*)&hl[swz(n * 16 + l15, hid >> 3) + (hid & 7)] = h4;
            }

        // ---- b2 reload (L2-hit, ~300cy ahead of GEMM2) ----
        f32x4 b2v[2];
#pragma unroll
        for (int m = 0; m < 2; ++m)
            b2v[m] = *(const f32x4*)&gb2[wb + m * 16 + g * 4];

        // ---- acc2 init: bias + residual x (b64 read from xs, pre-bar2) ----
        f32x4 acc2[2][2];
#pragma unroll
        for (int m = 0; m < 2; ++m)
#pragma unroll
            for (int n = 0; n < 2; ++n) {
                const int hid = wb + m * 16 + 4 * g;       // out-dim base
                bf16x4 rx = *(const bf16x4*)&xs[swz(n * 16 + l15, hid >> 3) + (hid & 7)];
                f32x4 t;
#pragma unroll
                for (int r = 0; r < 4; ++r)
                    t[r] = b2v[m][r] + (float)rx[r];
                acc2[m][n] = t;
            }
        __syncthreads();                                   // bar2

        // ---- GEMM2^T: out^T += W2^T @ h^T ----
#pragma unroll
        for (int ks = 0; ks < 4; ++ks) {
            bf16x8 bh[2];
#pragma unroll
            for (int n = 0; n < 2; ++n)
                bh[n] = *(const bf16x8*)&hl[swz(n * 16 + l15, ks * 4 + g)];
#pragma unroll
            for (int m = 0; m < 2; ++m)
#pragma unroll
                for (int n = 0; n < 2; ++n)
                    acc2[m][n] = __builtin_amdgcn_mfma_f32_16x16x32_bf16(
                        w2t[m][ks], bh[n], acc2[m][n], 0, 0, 0);
        }

        // ---- epilogue: plain float4 stores; wave covers [wb,wb+32) per row
        //      = one full aligned 128B line -> clean L2 write-combine ----
        const int e0 = tile * TILE_M;
#pragma unroll
        for (int n = 0; n < 2; ++n) {
            const size_t rowbase = (size_t)(e0 + n * 16 + l15) * 128;
#pragma unroll
            for (int m = 0; m < 2; ++m)
                *(f32x4*)&gout[rowbase + wb + m * 16 + g * 4] = acc2[m][n];
        }

        if (!have) break;
        tile = nxt;
    }
}

extern "C" void kernel_launch(void* const* d_in, const int* in_sizes, int n_in,
                              void* d_out, int out_size, void* d_ws, size_t ws_size,
                              hipStream_t stream) {
    const float* src = (const float*)d_in[0];
    const float* dst = (const float*)d_in[1];
    const float* ea  = (const float*)d_in[2];
    const float* u   = (const float*)d_in[3];
    const int*   bt  = (const int*)d_in[4];
    const float* w1  = (const float*)d_in[5];
    const float* b1  = (const float*)d_in[6];
    const float* w2  = (const float*)d_in[7];
    const float* b2  = (const float*)d_in[8];
    float* out = (float*)d_out;

    edge_mlp<<<GRID, 256, 0, stream>>>(src, dst, ea, u, bt, w1, b1, w2, b2, out);
}

// Round 14
// 179.235 us; speedup vs baseline: 1.1085x; 1.1085x over previous
//
#include <hip/hip_runtime.h>

// EdgeModel: out = relu(x@W1+b1)@W2 + b2 + x, x = [src|dest|ea|u[batch]].
// E=1e6, dims 128. bf16 MFMA 16x16x32, fp32 accum.
// R14 = R12 verbatim (best measured: 176.4 us). Structure: 64-edge tile,
// x staged to LDS bf16 XOR-swizzled, both GEMMs transposed (C rows = dims,
// cols = edges), h->LDS b64 writes, residual folded into acc2 init from xs,
// 2 barriers/tile, register prefetch 1 tile ahead, plain dwordx4 epilogue.
// Occupancy notes (rounds 6-13): any forced __launch_bounds__ >=3 spills
// (VGPR clamp 84 + scratch traffic); natural alloc sits at 2 waves/SIMD;
// TILE_M=32 halves reg footprint but doubles per-edge overhead (198 us).

#define E_TOTAL   1000000
#define TILE_M    64
#define NUM_TILES (E_TOTAL / TILE_M)   // 15625
#define GRID      2048

typedef __attribute__((ext_vector_type(8))) __bf16 bf16x8;
typedef __attribute__((ext_vector_type(4))) __bf16 bf16x4;
typedef __attribute__((ext_vector_type(4))) float  f32x4;

__device__ inline bf16x8 pack8(f32x4 v0, f32x4 v1) {
    bf16x8 r;
    r[0] = (__bf16)v0[0]; r[1] = (__bf16)v0[1];
    r[2] = (__bf16)v0[2]; r[3] = (__bf16)v0[3];
    r[4] = (__bf16)v1[0]; r[5] = (__bf16)v1[1];
    r[6] = (__bf16)v1[2]; r[7] = (__bf16)v1[3];
    return r;
}

// row-major [64][128] bf16, 16 groups of 8/row, group XOR (row&15):
// all b128 reads conflict-free.
__device__ inline int swz(int row, int group) {
    return (row * 16 + (group ^ (row & 15))) * 8;
}

__global__ __launch_bounds__(256, 2)
void edge_mlp(const float* __restrict__ gsrc,
              const float* __restrict__ gdst,
              const float* __restrict__ gea,
              const float* __restrict__ gu,
              const int*   __restrict__ gbatch,
              const float* __restrict__ gw1,
              const float* __restrict__ gb1,
              const float* __restrict__ gw2,
              const float* __restrict__ gb2,
              float* __restrict__ gout)
{
    __shared__ __align__(16) __bf16 xs[TILE_M * 128];   // x tile (bf16, swizzled)
    __shared__ __align__(16) __bf16 hl[TILE_M * 128];   // h tile (bf16, swizzled)

    const int tid  = threadIdx.x;
    const int lane = tid & 63;
    const int wid  = tid >> 6;     // wave owns hidden/out-dim rows [wb,wb+32)
    const int l15  = lane & 15;
    const int g    = lane >> 4;
    const int wb   = wid * 32;

    // ---- W1^T and W2^T as A-fragments (persistent, 64 regs):
    //      lane holds W^T[row = wb+m*16+l15][k = ks*32+g*8+j] = gw[k*128+row]
    bf16x8 w1t[2][4], w2t[2][4];
#pragma unroll
    for (int m = 0; m < 2; ++m)
#pragma unroll
        for (int ks = 0; ks < 4; ++ks) {
            bf16x8 t1, t2;
#pragma unroll
            for (int j = 0; j < 8; ++j) {
                const int k = ks * 32 + g * 8 + j;
                const int r = wb + m * 16 + l15;
                t1[j] = (__bf16)gw1[k * 128 + r];
                t2[j] = (__bf16)gw2[k * 128 + r];
            }
            w1t[m][ks] = t1;
            w2t[m][ks] = t2;
        }

    // ---- b1 along C rows (persistent; b2 reloaded per tile) ----
    f32x4 b1v[2];
#pragma unroll
    for (int m = 0; m < 2; ++m)
#pragma unroll
        for (int r = 0; r < 4; ++r)
            b1v[m][r] = gb1[wb + m * 16 + g * 4 + r];

    // ---- staging: thread t owns edge-row t>>2, 8-float chunk t&3 ----
    const int srow = tid >> 2;
    const int ssub = tid & 3;

    f32x4 pre[3][2];   // src/dest/ea only; u loaded at stage time (L1-resident)
    int   preb;        // prefetched batch index
    auto load_pre = [&](int t) {
        const int e = t * TILE_M + srow;
        preb = gbatch[e];
        const float* p0 = gsrc + (size_t)e * 32 + ssub * 8;
        const float* p1 = gdst + (size_t)e * 32 + ssub * 8;
        const float* p2 = gea  + (size_t)e * 32 + ssub * 8;
        pre[0][0] = *(const f32x4*)p0; pre[0][1] = *(const f32x4*)(p0 + 4);
        pre[1][0] = *(const f32x4*)p1; pre[1][1] = *(const f32x4*)(p1 + 4);
        pre[2][0] = *(const f32x4*)p2; pre[2][1] = *(const f32x4*)(p2 + 4);
    };

    int tile = blockIdx.x;
    load_pre(tile);

    while (true) {
        // ---- stage x tile into LDS (bf16, swizzled) ----
#pragma unroll
        for (int p = 0; p < 3; ++p)
            *(bf16x8*)&xs[swz(srow, p * 4 + ssub)] = pack8(pre[p][0], pre[p][1]);
        {   // u part: load now from L1-resident table (bi was prefetched)
            const float* q = gu + (size_t)preb * 32 + ssub * 8;
            f32x4 lo = *(const f32x4*)q;
            f32x4 hi = *(const f32x4*)(q + 4);
            *(bf16x8*)&xs[swz(srow, 12 + ssub)] = pack8(lo, hi);
        }
        __syncthreads();                                   // bar1

        const int  nxt  = tile + GRID;
        const bool have = nxt < NUM_TILES;
        if (have) load_pre(nxt);

        // ---- GEMM1^T: h^T = W1^T @ x^T + b1 ----
        f32x4 acc[2][4];
#pragma unroll
        for (int m = 0; m < 2; ++m)
#pragma unroll
            for (int n = 0; n < 4; ++n)
                acc[m][n] = b1v[m];
#pragma unroll
        for (int ks = 0; ks < 4; ++ks) {
            bf16x8 bf[4];
#pragma unroll
            for (int n = 0; n < 4; ++n)
                bf[n] = *(const bf16x8*)&xs[swz(n * 16 + l15, ks * 4 + g)];
#pragma unroll
            for (int m = 0; m < 2; ++m)
#pragma unroll
                for (int n = 0; n < 4; ++n)
                    acc[m][n] = __builtin_amdgcn_mfma_f32_16x16x32_bf16(
                        w1t[m][ks], bf[n], acc[m][n], 0, 0, 0);
        }

        // ---- ReLU + pack + h -> LDS (b64: 4 consecutive hidden dims) ----
#pragma unroll
        for (int m = 0; m < 2; ++m)
#pragma unroll
            for (int n = 0; n < 4; ++n) {
                f32x4 v = acc[m][n];
                bf16x4 h4;
#pragma unroll
                for (int r = 0; r < 4; ++r) {
                    float x = v[r];
                    h4[r] = (__bf16)(x > 0.f ? x : 0.f);
                }
                const int hid = wb + m * 16 + 4 * g;       // 4-aligned
                *(bf16x4*)&hl[swz(n * 16 + l15, hid >> 3) + (hid & 7)] = h4;
            }

        // ---- b2 reload (L2-hit, ~300cy ahead of GEMM2) ----
        f32x4 b2v[2];
#pragma unroll
        for (int m = 0; m < 2; ++m)
            b2v[m] = *(const f32x4*)&gb2[wb + m * 16 + g * 4];

        // ---- acc2 init: bias + residual x (b64 read from xs, pre-bar2) ----
        f32x4 acc2[2][4];
#pragma unroll
        for (int m = 0; m < 2; ++m)
#pragma unroll
            for (int n = 0; n < 4; ++n) {
                const int hid = wb + m * 16 + 4 * g;       // out-dim base, 4-aligned
                bf16x4 rx = *(const bf16x4*)&xs[swz(n * 16 + l15, hid >> 3) + (hid & 7)];
                f32x4 t;
#pragma unroll
                for (int r = 0; r < 4; ++r)
                    t[r] = b2v[m][r] + (float)rx[r];
                acc2[m][n] = t;
            }
        __syncthreads();                                   // bar2

        // ---- GEMM2^T: out^T += W2^T @ h^T ----
#pragma unroll
        for (int ks = 0; ks < 4; ++ks) {
            bf16x8 bh[4];
#pragma unroll
            for (int n = 0; n < 4; ++n)
                bh[n] = *(const bf16x8*)&hl[swz(n * 16 + l15, ks * 4 + g)];
#pragma unroll
            for (int m = 0; m < 2; ++m)
#pragma unroll
                for (int n = 0; n < 4; ++n)
                    acc2[m][n] = __builtin_amdgcn_mfma_f32_16x16x32_bf16(
                        w2t[m][ks], bh[n], acc2[m][n], 0, 0, 0);
        }

        // ---- epilogue: plain float4 stores (4 consecutive out dims) ----
        const int e0 = tile * TILE_M;
#pragma unroll
        for (int n = 0; n < 4; ++n) {
            const size_t rowbase = (size_t)(e0 + n * 16 + l15) * 128;
#pragma unroll
            for (int m = 0; m < 2; ++m)
                *(f32x4*)&gout[rowbase + wb + m * 16 + g * 4] = acc2[m][n];
        }

        if (!have) break;
        tile = nxt;
    }
}

extern "C" void kernel_launch(void* const* d_in, const int* in_sizes, int n_in,
                              void* d_out, int out_size, void* d_ws, size_t ws_size,
                              hipStream_t stream) {
    const float* src = (const float*)d_in[0];
    const float* dst = (const float*)d_in[1];
    const float* ea  = (const float*)d_in[2];
    const float* u   = (const float*)d_in[3];
    const int*   bt  = (const int*)d_in[4];
    const float* w1  = (const float*)d_in[5];
    const float* b1  = (const float*)d_in[6];
    const float* w2  = (const float*)d_in[7];
    const float* b2  = (const float*)d_in[8];
    float* out = (float*)d_out;

    edge_mlp<<<GRID, 256, 0, stream>>>(src, dst, ea, u, bt, w1, b1, w2, b2, out);
}